// Round 14
// baseline (372.733 us; speedup 1.0000x reference)
//
#include <hip/hip_runtime.h>
#include <hip/hip_bf16.h>

#define N_NODES 150000
#define M_HYPER 50000
#define N_TOTAL 200000
#define DIM 64
#define NCLASS 50
#define NNZ 3200000

#define BSHIFT 9
#define BROWS 512
#define NBUK ((N_TOTAL + BROWS - 1) / BROWS)  // 391
#define EB 8192                               // edges per binning block
#define CAP 9216                              // fixed bucket capacity (11 sigma)

// Stored fp8 values carry a global x64 scale (encode 64*true, decode *1/64).
#define SCALE_UP 64.0f
#define SCALE_DN 0.015625f
// Edge value quantization: q = round(val * 163840), val = q / 163840.
#define VQ_ENC 163840.0f
#define VQ_DEC 6.103515625e-6f

typedef float v2f __attribute__((ext_vector_type(2)));

// ---------------------------------------------------------------------------
// Init fixed-capacity cursors: bcur[b] = b * CAP
// ---------------------------------------------------------------------------
__global__ __launch_bounds__(512) void init_cur(int* __restrict__ bcur) {
    int t = threadIdx.x;
    if (t < NBUK) bcur[t] = t * CAP;
}

// ---------------------------------------------------------------------------
// Phase A: bin edges into fixed-capacity bucket regions, LDS-aggregated.
// rec.x = (rrel << 18) | col, rec.y = val quantized to 14 bits
// ---------------------------------------------------------------------------
__global__ __launch_bounds__(1024) void bin_edges(
    const int* __restrict__ rows, const int* __restrict__ cols,
    const float* __restrict__ vals, int* __restrict__ bcur,
    int2* __restrict__ recs) {
    __shared__ int h[NBUK];
    __shared__ int lbase[NBUK];
    int base = blockIdx.x * EB;
    int cntE = NNZ - base; if (cntE > EB) cntE = EB;
    for (int i = threadIdx.x; i < NBUK; i += 1024) h[i] = 0;
    __syncthreads();
    for (int i = threadIdx.x; i < cntE; i += 1024)
        atomicAdd(&h[rows[base + i] >> BSHIFT], 1);
    __syncthreads();
    for (int i = threadIdx.x; i < NBUK; i += 1024) {
        int c = h[i];
        lbase[i] = c ? atomicAdd(&bcur[i], c) : 0;
    }
    __syncthreads();
    for (int i = threadIdx.x; i < NBUK; i += 1024) h[i] = 0;
    __syncthreads();
    for (int i = threadIdx.x; i < cntE; i += 1024) {
        int e = base + i;
        int r = rows[e];
        int b = r >> BSHIFT;
        int p = lbase[b] + atomicAdd(&h[b], 1);
        int q = __float2int_rn(vals[e] * VQ_ENC);
        if (q > 16383) q = 16383;
        if (p < NBUK * CAP)  // statistically impossible overflow guard
            recs[p] = make_int2(((r & (BROWS - 1)) << 18) | cols[e], q);
    }
}

// ---------------------------------------------------------------------------
// Exclusive scan over actual bucket counts (bcur[b] - b*CAP) -> compact boff
// ---------------------------------------------------------------------------
__global__ __launch_bounds__(512) void cnt_scan(const int* __restrict__ bcur,
                                                int* __restrict__ boff) {
    __shared__ int sh[512];
    int t = threadIdx.x;
    int c = (t < NBUK) ? (bcur[t] - t * CAP) : 0;
    sh[t] = c;
    __syncthreads();
    for (int off = 1; off < 512; off <<= 1) {
        int v = (t >= off) ? sh[t - off] : 0;
        __syncthreads();
        sh[t] += v;
        __syncthreads();
    }
    if (t < NBUK) boff[t] = sh[t] - c;  // exclusive
    if (t == 0) boff[NBUK] = NNZ;
}

// ---------------------------------------------------------------------------
// Phase B: per-bucket CSR build, column-block-sorted within each row.
// Key = (rrel << 3) | (col >> 15): 8 col-blocks of 32768 rows (2.1 MB fp8).
// Thread t owns row rrel=t (8 keys). Edges within a row come out ordered by
// col-block -> cross-wave gather locality in spmm (active window fits L2).
// Output edge = (q14 << 18) | col (4 bytes).
// ---------------------------------------------------------------------------
__global__ __launch_bounds__(512) void build_csr(const int* __restrict__ boff,
                                                 const int2* __restrict__ recs,
                                                 int* __restrict__ row_ptr,
                                                 unsigned* __restrict__ edges) {
    __shared__ int h[BROWS * 8];   // per-(row, col-block) counts -> cursors
    __shared__ int ps[512];
    int b = blockIdx.x, t = threadIdx.x;
    int rbase = b * CAP;
    int obase = boff[b];
    int cnt = boff[b + 1] - obase;
    int row0 = b << BSHIFT;
    int nrows = N_TOTAL - row0;
    if (nrows > BROWS) nrows = BROWS;
    for (int i = t; i < BROWS * 8; i += 512) h[i] = 0;
    __syncthreads();
    for (int i = t; i < cnt; i += 512) {
        int rx = recs[rbase + i].x;
        int key = ((rx >> 18) << 3) | ((rx & 0x3FFFF) >> 15);
        atomicAdd(&h[key], 1);
    }
    __syncthreads();
    // Thread t owns keys [8t, 8t+8) == row t's 8 col-block counts.
    int loc[8];
    int s = 0;
#pragma unroll
    for (int j = 0; j < 8; ++j) { loc[j] = h[8 * t + j]; s += loc[j]; }
    ps[t] = s;
    __syncthreads();
    for (int off = 1; off < 512; off <<= 1) {
        int a = (t >= off) ? ps[t - off] : 0;
        __syncthreads();
        ps[t] += a;
        __syncthreads();
    }
    int run = obase + ((t == 0) ? 0 : ps[t - 1]);
    if (t < nrows) row_ptr[row0 + t] = run;
    if (b == NBUK - 1 && t == 0) row_ptr[N_TOTAL] = NNZ;
#pragma unroll
    for (int j = 0; j < 8; ++j) { h[8 * t + j] = run; run += loc[j]; }
    __syncthreads();
    for (int i = t; i < cnt; i += 512) {
        int2 rc = recs[rbase + i];
        int key = ((rc.x >> 18) << 3) | ((rc.x & 0x3FFFF) >> 15);
        int p = atomicAdd(&h[key], 1);
        edges[p] = (unsigned)(rc.x & 0x3FFFF) | ((unsigned)rc.y << 18);
    }
}

// ---------------------------------------------------------------------------
// Build fp8 all_emb (x64 scale) from f32 node_emb / hyper_emb, HW encode.
// ---------------------------------------------------------------------------
__global__ __launch_bounds__(256) void build_x_fp8(
    const float* __restrict__ node_emb, const float* __restrict__ hyper_emb,
    unsigned* __restrict__ xb) {
    int i = blockIdx.x * 256 + threadIdx.x;
    size_t base = (size_t)i * 4;
    const size_t NN = (size_t)N_NODES * DIM;
    if (base >= (size_t)N_TOTAL * DIM) return;
    float4 f;
    if (base < NN)
        f = *reinterpret_cast<const float4*>(node_emb + base);
    else
        f = *reinterpret_cast<const float4*>(hyper_emb + (base - NN));
    int lo = __builtin_amdgcn_cvt_pk_fp8_f32(f.x * SCALE_UP, f.y * SCALE_UP,
                                             0, false);
    int w = __builtin_amdgcn_cvt_pk_fp8_f32(f.z * SCALE_UP, f.w * SCALE_UP,
                                            lo, true);
    xb[i] = (unsigned)w;
}

// ---------------------------------------------------------------------------
// SpMM gather: 32 lanes per row (lane = 2 dims via 2 fp8), 2 rows per wave,
// unroll x8 per row. HW fp8 decode. Edges are 4B packed, col-block-ordered.
// ---------------------------------------------------------------------------
__global__ __launch_bounds__(256) void spmm_gather(
    const int* __restrict__ row_ptr, const unsigned* __restrict__ edges,
    const unsigned char* __restrict__ x, unsigned char* __restrict__ y,
    int nrows) {
    int gid = blockIdx.x * 256 + threadIdx.x;
    int row = gid >> 5;
    int lane = threadIdx.x & 31;
    if (row >= nrows) return;
    int beg = row_ptr[row], end = row_ptr[row + 1];
    float rx = 0.f, ry = 0.f;
    int k = beg;
    for (; k + 7 < end; k += 8) {
        unsigned e[8];
        unsigned g[8];
#pragma unroll
        for (int j = 0; j < 8; ++j) e[j] = __builtin_nontemporal_load(edges + k + j);
#pragma unroll
        for (int j = 0; j < 8; ++j)
            g[j] = *(const unsigned short*)(x + ((size_t)(e[j] & 0x3FFFFu) << 6) + lane * 2);
#pragma unroll
        for (int j = 0; j < 8; ++j) {
            float v = (float)(e[j] >> 18) * VQ_DEC;
            v2f f = __builtin_amdgcn_cvt_pk_f32_fp8((int)g[j], false);
            rx = fmaf(v, f[0], rx);
            ry = fmaf(v, f[1], ry);
        }
    }
    for (; k + 3 < end; k += 4) {
        unsigned e[4];
        unsigned g[4];
#pragma unroll
        for (int j = 0; j < 4; ++j) e[j] = __builtin_nontemporal_load(edges + k + j);
#pragma unroll
        for (int j = 0; j < 4; ++j)
            g[j] = *(const unsigned short*)(x + ((size_t)(e[j] & 0x3FFFFu) << 6) + lane * 2);
#pragma unroll
        for (int j = 0; j < 4; ++j) {
            float v = (float)(e[j] >> 18) * VQ_DEC;
            v2f f = __builtin_amdgcn_cvt_pk_f32_fp8((int)g[j], false);
            rx = fmaf(v, f[0], rx);
            ry = fmaf(v, f[1], ry);
        }
    }
    for (; k < end; ++k) {
        unsigned e = __builtin_nontemporal_load(edges + k);
        unsigned g = *(const unsigned short*)(x + ((size_t)(e & 0x3FFFFu) << 6) + lane * 2);
        float v = (float)(e >> 18) * VQ_DEC;
        v2f f = __builtin_amdgcn_cvt_pk_f32_fp8((int)g, false);
        rx = fmaf(v, f[0], rx);
        ry = fmaf(v, f[1], ry);
    }
    int pk = __builtin_amdgcn_cvt_pk_fp8_f32(rx, ry, 0, false);
    *(unsigned short*)(y + ((size_t)row << 6) + lane * 2) = (unsigned short)pk;
}

// ---------------------------------------------------------------------------
// Fused classifier: Z = log_softmax((node_emb + (y1+y2+y3)/64)/4 @ W + b)
// ---------------------------------------------------------------------------
__global__ __launch_bounds__(256) void classify(
    const float* __restrict__ node_emb, const unsigned char* __restrict__ y1,
    const unsigned char* __restrict__ y2,
    const unsigned char* __restrict__ y3, const float* __restrict__ W,
    const float* __restrict__ bias, float* __restrict__ Z) {
    int row = blockIdx.x * 256 + threadIdx.x;
    if (row >= N_NODES) return;
    const float4* np =
        reinterpret_cast<const float4*>(node_emb + (size_t)row * DIM);
    const unsigned* p1 = (const unsigned*)(y1 + ((size_t)row << 6));
    const unsigned* p2 = (const unsigned*)(y2 + ((size_t)row << 6));
    const unsigned* p3 = (const unsigned*)(y3 + ((size_t)row << 6));
    float xr[DIM];
#pragma unroll
    for (int i = 0; i < DIM / 4; ++i) {
        float4 f = np[i];
        unsigned w1 = p1[i], w2 = p2[i], w3 = p3[i];
        v2f a0 = __builtin_amdgcn_cvt_pk_f32_fp8((int)w1, false);
        v2f a1 = __builtin_amdgcn_cvt_pk_f32_fp8((int)w1, true);
        v2f b0 = __builtin_amdgcn_cvt_pk_f32_fp8((int)w2, false);
        v2f b1 = __builtin_amdgcn_cvt_pk_f32_fp8((int)w2, true);
        v2f c0 = __builtin_amdgcn_cvt_pk_f32_fp8((int)w3, false);
        v2f c1 = __builtin_amdgcn_cvt_pk_f32_fp8((int)w3, true);
        xr[4 * i + 0] = (f.x + (a0[0] + b0[0] + c0[0]) * SCALE_DN) * 0.25f;
        xr[4 * i + 1] = (f.y + (a0[1] + b0[1] + c0[1]) * SCALE_DN) * 0.25f;
        xr[4 * i + 2] = (f.z + (a1[0] + b1[0] + c1[0]) * SCALE_DN) * 0.25f;
        xr[4 * i + 3] = (f.w + (a1[1] + b1[1] + c1[1]) * SCALE_DN) * 0.25f;
    }
    float m = -1e30f, s = 0.f;
#pragma unroll 1
    for (int c = 0; c < NCLASS; ++c) {
        float d = bias[c];
#pragma unroll
        for (int k = 0; k < DIM; ++k) d = fmaf(xr[k], W[k * NCLASS + c], d);
        float mn = fmaxf(m, d);
        s = s * __expf(m - mn) + __expf(d - mn);
        m = mn;
    }
    float ls = m + __logf(s);
    float* zp = Z + (size_t)row * NCLASS;
#pragma unroll 1
    for (int c = 0; c < NCLASS; ++c) {
        float d = bias[c];
#pragma unroll
        for (int k = 0; k < DIM; ++k) d = fmaf(xr[k], W[k * NCLASS + c], d);
        zp[c] = d - ls;
    }
}

extern "C" void kernel_launch(void* const* d_in, const int* in_sizes, int n_in,
                              void* d_out, int out_size, void* d_ws, size_t ws_size,
                              hipStream_t stream) {
    const float* node_emb = (const float*)d_in[0];
    const float* hyper_emb = (const float*)d_in[1];
    const float* W = (const float*)d_in[2];
    const float* b = (const float*)d_in[3];
    const float* vals = (const float*)d_in[4];
    const int* rows = (const int*)d_in[5];
    const int* cols = (const int*)d_in[6];
    float* Z = (float*)d_out;

    const size_t BUF8 = (size_t)N_TOTAL * DIM;  // 12.8 MB (fp8)
    const size_t EDG = (size_t)NNZ * 4;         // 12.8 MB (packed u32)

    char* w = (char*)d_ws;
    unsigned char* xb = (unsigned char*)w;  w += BUF8;
    unsigned char* y1 = (unsigned char*)w;  w += BUF8;
    unsigned char* y2 = (unsigned char*)w;  w += BUF8;
    unsigned char* y3 = (unsigned char*)w;  w += BUF8;
    unsigned* edges = (unsigned*)w;         w += EDG;
    int* row_ptr = (int*)w;                 w += (size_t)(N_TOTAL + 1) * 4;
    int* boff = (int*)w;                    w += 2048;
    int* bcur = (int*)w;                    w += 2048;
    // recs (28.8 MB) in dedicated tail space (dead after build_csr).
    int2* recs = (int2*)w;

    // ---- Bucketed CSR build (fixed-capacity regions, no pre-histogram) ----
    init_cur<<<1, 512, 0, stream>>>(bcur);
    const int bin_blocks = (NNZ + EB - 1) / EB;  // 391
    bin_edges<<<bin_blocks, 1024, 0, stream>>>(rows, cols, vals, bcur, recs);
    cnt_scan<<<1, 512, 0, stream>>>(bcur, boff);
    build_csr<<<NBUK, 512, 0, stream>>>(boff, recs, row_ptr, edges);

    // ---- Build fp8 all_emb ----
    const int cvt_blocks = (int)(((size_t)N_TOTAL * DIM / 4 + 255) / 256);
    build_x_fp8<<<cvt_blocks, 256, 0, stream>>>(node_emb, hyper_emb,
                                                (unsigned*)xb);

    const int out_blocks = (N_NODES + 255) / 256;
    const int full_blocks = (N_TOTAL * 32 + 255) / 256;
    const int node_blocks = (N_NODES * 32 + 255) / 256;

    // L1: y1 = A x
    spmm_gather<<<full_blocks, 256, 0, stream>>>(row_ptr, edges, xb, y1,
                                                 N_TOTAL);
    // L2: y2 = A y1
    spmm_gather<<<full_blocks, 256, 0, stream>>>(row_ptr, edges, y1, y2,
                                                 N_TOTAL);
    // L3: y3 = A y2 (node rows only)
    spmm_gather<<<node_blocks, 256, 0, stream>>>(row_ptr, edges, y2, y3,
                                                 N_NODES);
    classify<<<out_blocks, 256, 0, stream>>>(node_emb, y1, y2, y3, W, b, Z);
}

// Round 15
// 293.219 us; speedup vs baseline: 1.2712x; 1.2712x over previous
//
#include <hip/hip_runtime.h>
#include <hip/hip_bf16.h>

#define N_NODES 150000
#define M_HYPER 50000
#define N_TOTAL 200000
#define DIM 64
#define NCLASS 50
#define NNZ 3200000

#define BSHIFT 9
#define BROWS 512
#define NBUK ((N_TOTAL + BROWS - 1) / BROWS)  // 391
#define EB 8192                               // edges per binning block
#define CAP 9216                              // fixed bucket capacity (11 sigma)

// Stored fp8 values carry a global x64 scale (encode 64*true, decode *1/64).
#define SCALE_UP 64.0f
#define SCALE_DN 0.015625f
// Edge value quantization: q = round(val * 163840), val = q / 163840.
#define VQ_ENC 163840.0f
#define VQ_DEC 6.103515625e-6f

typedef float v2f __attribute__((ext_vector_type(2)));

// ---------------------------------------------------------------------------
// Init fixed-capacity cursors: bcur[b] = b * CAP
// ---------------------------------------------------------------------------
__global__ __launch_bounds__(512) void init_cur(int* __restrict__ bcur) {
    int t = threadIdx.x;
    if (t < NBUK) bcur[t] = t * CAP;
}

// ---------------------------------------------------------------------------
// Phase A: bin edges into fixed-capacity bucket regions, LDS-aggregated.
// rec.x = (rrel << 18) | col, rec.y = val quantized to 14 bits
// ---------------------------------------------------------------------------
__global__ __launch_bounds__(1024) void bin_edges(
    const int* __restrict__ rows, const int* __restrict__ cols,
    const float* __restrict__ vals, int* __restrict__ bcur,
    int2* __restrict__ recs) {
    __shared__ int h[NBUK];
    __shared__ int lbase[NBUK];
    int base = blockIdx.x * EB;
    int cntE = NNZ - base; if (cntE > EB) cntE = EB;
    for (int i = threadIdx.x; i < NBUK; i += 1024) h[i] = 0;
    __syncthreads();
    for (int i = threadIdx.x; i < cntE; i += 1024)
        atomicAdd(&h[rows[base + i] >> BSHIFT], 1);
    __syncthreads();
    for (int i = threadIdx.x; i < NBUK; i += 1024) {
        int c = h[i];
        lbase[i] = c ? atomicAdd(&bcur[i], c) : 0;
    }
    __syncthreads();
    for (int i = threadIdx.x; i < NBUK; i += 1024) h[i] = 0;
    __syncthreads();
    for (int i = threadIdx.x; i < cntE; i += 1024) {
        int e = base + i;
        int r = rows[e];
        int b = r >> BSHIFT;
        int p = lbase[b] + atomicAdd(&h[b], 1);
        int q = __float2int_rn(vals[e] * VQ_ENC);
        if (q > 16383) q = 16383;
        if (p < NBUK * CAP)  // statistically impossible overflow guard
            recs[p] = make_int2(((r & (BROWS - 1)) << 18) | cols[e], q);
    }
}

// ---------------------------------------------------------------------------
// Exclusive scan over actual bucket counts (bcur[b] - b*CAP) -> compact boff
// ---------------------------------------------------------------------------
__global__ __launch_bounds__(512) void cnt_scan(const int* __restrict__ bcur,
                                                int* __restrict__ boff) {
    __shared__ int sh[512];
    int t = threadIdx.x;
    int c = (t < NBUK) ? (bcur[t] - t * CAP) : 0;
    sh[t] = c;
    __syncthreads();
    for (int off = 1; off < 512; off <<= 1) {
        int v = (t >= off) ? sh[t - off] : 0;
        __syncthreads();
        sh[t] += v;
        __syncthreads();
    }
    if (t < NBUK) boff[t] = sh[t] - c;  // exclusive
    if (t == 0) boff[NBUK] = NNZ;
}

// ---------------------------------------------------------------------------
// Phase B: per-bucket CSR build (col-block keyed: 8 keys/row spreads LDS
// atomics). Output edge = (q14 << 18) | col (4 bytes).
// ---------------------------------------------------------------------------
__global__ __launch_bounds__(512) void build_csr(const int* __restrict__ boff,
                                                 const int2* __restrict__ recs,
                                                 int* __restrict__ row_ptr,
                                                 unsigned* __restrict__ edges) {
    __shared__ int h[BROWS * 8];   // per-(row, col-block) counts -> cursors
    __shared__ int ps[512];
    int b = blockIdx.x, t = threadIdx.x;
    int rbase = b * CAP;
    int obase = boff[b];
    int cnt = boff[b + 1] - obase;
    int row0 = b << BSHIFT;
    int nrows = N_TOTAL - row0;
    if (nrows > BROWS) nrows = BROWS;
    for (int i = t; i < BROWS * 8; i += 512) h[i] = 0;
    __syncthreads();
    for (int i = t; i < cnt; i += 512) {
        int rx = recs[rbase + i].x;
        int key = ((rx >> 18) << 3) | ((rx & 0x3FFFF) >> 15);
        atomicAdd(&h[key], 1);
    }
    __syncthreads();
    int loc[8];
    int s = 0;
#pragma unroll
    for (int j = 0; j < 8; ++j) { loc[j] = h[8 * t + j]; s += loc[j]; }
    ps[t] = s;
    __syncthreads();
    for (int off = 1; off < 512; off <<= 1) {
        int a = (t >= off) ? ps[t - off] : 0;
        __syncthreads();
        ps[t] += a;
        __syncthreads();
    }
    int run = obase + ((t == 0) ? 0 : ps[t - 1]);
    if (t < nrows) row_ptr[row0 + t] = run;
    if (b == NBUK - 1 && t == 0) row_ptr[N_TOTAL] = NNZ;
#pragma unroll
    for (int j = 0; j < 8; ++j) { h[8 * t + j] = run; run += loc[j]; }
    __syncthreads();
    for (int i = t; i < cnt; i += 512) {
        int2 rc = recs[rbase + i];
        int key = ((rc.x >> 18) << 3) | ((rc.x & 0x3FFFF) >> 15);
        int p = atomicAdd(&h[key], 1);
        edges[p] = (unsigned)(rc.x & 0x3FFFF) | ((unsigned)rc.y << 18);
    }
}

// ---------------------------------------------------------------------------
// Build fp8 all_emb (x64 scale) from f32 node_emb / hyper_emb, HW encode.
// ---------------------------------------------------------------------------
__global__ __launch_bounds__(256) void build_x_fp8(
    const float* __restrict__ node_emb, const float* __restrict__ hyper_emb,
    unsigned* __restrict__ xb) {
    int i = blockIdx.x * 256 + threadIdx.x;
    size_t base = (size_t)i * 4;
    const size_t NN = (size_t)N_NODES * DIM;
    if (base >= (size_t)N_TOTAL * DIM) return;
    float4 f;
    if (base < NN)
        f = *reinterpret_cast<const float4*>(node_emb + base);
    else
        f = *reinterpret_cast<const float4*>(hyper_emb + (base - NN));
    int lo = __builtin_amdgcn_cvt_pk_fp8_f32(f.x * SCALE_UP, f.y * SCALE_UP,
                                             0, false);
    int w = __builtin_amdgcn_cvt_pk_fp8_f32(f.z * SCALE_UP, f.w * SCALE_UP,
                                            lo, true);
    xb[i] = (unsigned)w;
}

// ---------------------------------------------------------------------------
// SpMM gather: 16 lanes per row (lane = 4 dims via one u32), 4 rows per wave,
// unroll x8 per row -> 32 outstanding 64B sectors per wave.
// ---------------------------------------------------------------------------
__global__ __launch_bounds__(256) void spmm_gather(
    const int* __restrict__ row_ptr, const unsigned* __restrict__ edges,
    const unsigned char* __restrict__ x, unsigned char* __restrict__ y,
    int nrows) {
    int gid = blockIdx.x * 256 + threadIdx.x;
    int row = gid >> 4;
    int lane = threadIdx.x & 15;
    if (row >= nrows) return;
    int beg = row_ptr[row], end = row_ptr[row + 1];
    float a0 = 0.f, a1 = 0.f, a2 = 0.f, a3 = 0.f;
    int k = beg;
    for (; k + 7 < end; k += 8) {
        unsigned e[8];
        unsigned g[8];
#pragma unroll
        for (int j = 0; j < 8; ++j) e[j] = edges[k + j];
#pragma unroll
        for (int j = 0; j < 8; ++j)
            g[j] = *(const unsigned*)(x + ((size_t)(e[j] & 0x3FFFFu) << 6) + lane * 4);
#pragma unroll
        for (int j = 0; j < 8; ++j) {
            float v = (float)(e[j] >> 18) * VQ_DEC;
            v2f lo = __builtin_amdgcn_cvt_pk_f32_fp8((int)g[j], false);
            v2f hi = __builtin_amdgcn_cvt_pk_f32_fp8((int)g[j], true);
            a0 = fmaf(v, lo[0], a0);
            a1 = fmaf(v, lo[1], a1);
            a2 = fmaf(v, hi[0], a2);
            a3 = fmaf(v, hi[1], a3);
        }
    }
    for (; k + 3 < end; k += 4) {
        unsigned e[4];
        unsigned g[4];
#pragma unroll
        for (int j = 0; j < 4; ++j) e[j] = edges[k + j];
#pragma unroll
        for (int j = 0; j < 4; ++j)
            g[j] = *(const unsigned*)(x + ((size_t)(e[j] & 0x3FFFFu) << 6) + lane * 4);
#pragma unroll
        for (int j = 0; j < 4; ++j) {
            float v = (float)(e[j] >> 18) * VQ_DEC;
            v2f lo = __builtin_amdgcn_cvt_pk_f32_fp8((int)g[j], false);
            v2f hi = __builtin_amdgcn_cvt_pk_f32_fp8((int)g[j], true);
            a0 = fmaf(v, lo[0], a0);
            a1 = fmaf(v, lo[1], a1);
            a2 = fmaf(v, hi[0], a2);
            a3 = fmaf(v, hi[1], a3);
        }
    }
    for (; k < end; ++k) {
        unsigned e = edges[k];
        unsigned g = *(const unsigned*)(x + ((size_t)(e & 0x3FFFFu) << 6) + lane * 4);
        float v = (float)(e >> 18) * VQ_DEC;
        v2f lo = __builtin_amdgcn_cvt_pk_f32_fp8((int)g, false);
        v2f hi = __builtin_amdgcn_cvt_pk_f32_fp8((int)g, true);
        a0 = fmaf(v, lo[0], a0);
        a1 = fmaf(v, lo[1], a1);
        a2 = fmaf(v, hi[0], a2);
        a3 = fmaf(v, hi[1], a3);
    }
    int plo = __builtin_amdgcn_cvt_pk_fp8_f32(a0, a1, 0, false);
    int pk = __builtin_amdgcn_cvt_pk_fp8_f32(a2, a3, plo, true);
    *(unsigned*)(y + ((size_t)row << 6) + lane * 4) = (unsigned)pk;
}

// ---------------------------------------------------------------------------
// Fused classifier: Z = log_softmax((node_emb + (y1+y2+y3)/64)/4 @ W + b)
// ---------------------------------------------------------------------------
__global__ __launch_bounds__(256) void classify(
    const float* __restrict__ node_emb, const unsigned char* __restrict__ y1,
    const unsigned char* __restrict__ y2,
    const unsigned char* __restrict__ y3, const float* __restrict__ W,
    const float* __restrict__ bias, float* __restrict__ Z) {
    int row = blockIdx.x * 256 + threadIdx.x;
    if (row >= N_NODES) return;
    const float4* np =
        reinterpret_cast<const float4*>(node_emb + (size_t)row * DIM);
    const unsigned* p1 = (const unsigned*)(y1 + ((size_t)row << 6));
    const unsigned* p2 = (const unsigned*)(y2 + ((size_t)row << 6));
    const unsigned* p3 = (const unsigned*)(y3 + ((size_t)row << 6));
    float xr[DIM];
#pragma unroll
    for (int i = 0; i < DIM / 4; ++i) {
        float4 f = np[i];
        unsigned w1 = p1[i], w2 = p2[i], w3 = p3[i];
        v2f a0 = __builtin_amdgcn_cvt_pk_f32_fp8((int)w1, false);
        v2f a1 = __builtin_amdgcn_cvt_pk_f32_fp8((int)w1, true);
        v2f b0 = __builtin_amdgcn_cvt_pk_f32_fp8((int)w2, false);
        v2f b1 = __builtin_amdgcn_cvt_pk_f32_fp8((int)w2, true);
        v2f c0 = __builtin_amdgcn_cvt_pk_f32_fp8((int)w3, false);
        v2f c1 = __builtin_amdgcn_cvt_pk_f32_fp8((int)w3, true);
        xr[4 * i + 0] = (f.x + (a0[0] + b0[0] + c0[0]) * SCALE_DN) * 0.25f;
        xr[4 * i + 1] = (f.y + (a0[1] + b0[1] + c0[1]) * SCALE_DN) * 0.25f;
        xr[4 * i + 2] = (f.z + (a1[0] + b1[0] + c1[0]) * SCALE_DN) * 0.25f;
        xr[4 * i + 3] = (f.w + (a1[1] + b1[1] + c1[1]) * SCALE_DN) * 0.25f;
    }
    float m = -1e30f, s = 0.f;
#pragma unroll 1
    for (int c = 0; c < NCLASS; ++c) {
        float d = bias[c];
#pragma unroll
        for (int k = 0; k < DIM; ++k) d = fmaf(xr[k], W[k * NCLASS + c], d);
        float mn = fmaxf(m, d);
        s = s * __expf(m - mn) + __expf(d - mn);
        m = mn;
    }
    float ls = m + __logf(s);
    float* zp = Z + (size_t)row * NCLASS;
#pragma unroll 1
    for (int c = 0; c < NCLASS; ++c) {
        float d = bias[c];
#pragma unroll
        for (int k = 0; k < DIM; ++k) d = fmaf(xr[k], W[k * NCLASS + c], d);
        zp[c] = d - ls;
    }
}

extern "C" void kernel_launch(void* const* d_in, const int* in_sizes, int n_in,
                              void* d_out, int out_size, void* d_ws, size_t ws_size,
                              hipStream_t stream) {
    const float* node_emb = (const float*)d_in[0];
    const float* hyper_emb = (const float*)d_in[1];
    const float* W = (const float*)d_in[2];
    const float* b = (const float*)d_in[3];
    const float* vals = (const float*)d_in[4];
    const int* rows = (const int*)d_in[5];
    const int* cols = (const int*)d_in[6];
    float* Z = (float*)d_out;

    const size_t BUF8 = (size_t)N_TOTAL * DIM;  // 12.8 MB (fp8)
    const size_t EDG = (size_t)NNZ * 4;         // 12.8 MB (packed u32)

    char* w = (char*)d_ws;
    unsigned char* xb = (unsigned char*)w;  w += BUF8;
    unsigned char* y1 = (unsigned char*)w;  w += BUF8;
    unsigned char* y2 = (unsigned char*)w;  w += BUF8;
    unsigned char* y3 = (unsigned char*)w;  w += BUF8;
    unsigned* edges = (unsigned*)w;         w += EDG;
    int* row_ptr = (int*)w;                 w += (size_t)(N_TOTAL + 1) * 4;
    int* boff = (int*)w;                    w += 2048;
    int* bcur = (int*)w;                    w += 2048;
    // recs (28.8 MB) in dedicated tail space (dead after build_csr).
    int2* recs = (int2*)w;

    // ---- Bucketed CSR build (fixed-capacity regions, no pre-histogram) ----
    init_cur<<<1, 512, 0, stream>>>(bcur);
    const int bin_blocks = (NNZ + EB - 1) / EB;  // 391
    bin_edges<<<bin_blocks, 1024, 0, stream>>>(rows, cols, vals, bcur, recs);
    cnt_scan<<<1, 512, 0, stream>>>(bcur, boff);
    build_csr<<<NBUK, 512, 0, stream>>>(boff, recs, row_ptr, edges);

    // ---- Build fp8 all_emb ----
    const int cvt_blocks = (int)(((size_t)N_TOTAL * DIM / 4 + 255) / 256);
    build_x_fp8<<<cvt_blocks, 256, 0, stream>>>(node_emb, hyper_emb,
                                                (unsigned*)xb);

    const int out_blocks = (N_NODES + 255) / 256;
    const int full_blocks = (N_TOTAL * 16 + 255) / 256;
    const int node_blocks = (N_NODES * 16 + 255) / 256;

    // L1: y1 = A x
    spmm_gather<<<full_blocks, 256, 0, stream>>>(row_ptr, edges, xb, y1,
                                                 N_TOTAL);
    // L2: y2 = A y1
    spmm_gather<<<full_blocks, 256, 0, stream>>>(row_ptr, edges, y1, y2,
                                                 N_TOTAL);
    // L3: y3 = A y2 (node rows only)
    spmm_gather<<<node_blocks, 256, 0, stream>>>(row_ptr, edges, y2, y3,
                                                 N_NODES);
    classify<<<out_blocks, 256, 0, stream>>>(node_emb, y1, y2, y3, W, b, Z);
}

// Round 16
// 262.979 us; speedup vs baseline: 1.4174x; 1.1150x over previous
//
#include <hip/hip_runtime.h>
#include <hip/hip_bf16.h>

#define N_NODES 150000
#define M_HYPER 50000
#define N_TOTAL 200000
#define DIM 64
#define NCLASS 50
#define NNZ 3200000

#define BSHIFT 9
#define BROWS 512
#define NBUK ((N_TOTAL + BROWS - 1) / BROWS)  // 391
#define EB 8192                               // edges per binning block
#define CAP 9216                              // fixed bucket capacity (11 sigma)

// Stored fp8 values carry a global x64 scale (encode 64*true, decode *1/64).
#define SCALE_UP 64.0f
#define SCALE_DN 0.015625f
// Edge value quantization: q = round(val * 163840), val = q / 163840.
#define VQ_ENC 163840.0f
#define VQ_DEC 6.103515625e-6f

typedef float v2f __attribute__((ext_vector_type(2)));

// ---------------------------------------------------------------------------
// Init fixed-capacity cursors: bcur[b] = b * CAP
// ---------------------------------------------------------------------------
__global__ __launch_bounds__(512) void init_cur(int* __restrict__ bcur) {
    int t = threadIdx.x;
    if (t < NBUK) bcur[t] = t * CAP;
}

// ---------------------------------------------------------------------------
// Phase A: bin edges into fixed-capacity bucket regions.
// Block-local counting sort in LDS, then linear LDS->global copy so the
// scattered-cursor writes become full-line coalesced streams.
// rec.x = (row << 14) | q14, rec.y = col
// ---------------------------------------------------------------------------
__global__ __launch_bounds__(1024) void bin_edges(
    const int* __restrict__ rows, const int* __restrict__ cols,
    const float* __restrict__ vals, int* __restrict__ bcur,
    int2* __restrict__ recs) {
    __shared__ int2 stage[EB];   // 64 KB
    __shared__ int h[NBUK];
    __shared__ int lsb[NBUK];    // LDS exclusive base per bucket
    __shared__ int lb[NBUK];     // global chunk base per bucket
    __shared__ int ps[512];
    int t = threadIdx.x;
    int base = blockIdx.x * EB;
    int cntE = NNZ - base; if (cntE > EB) cntE = EB;
    for (int i = t; i < NBUK; i += 1024) h[i] = 0;
    __syncthreads();
    for (int i = t; i < cntE; i += 1024)
        atomicAdd(&h[rows[base + i] >> BSHIFT], 1);
    __syncthreads();
    if (t < 512) ps[t] = (t < NBUK) ? h[t] : 0;
    __syncthreads();
    for (int off = 1; off < 512; off <<= 1) {
        int v = 0;
        if (t < 512 && t >= off) v = ps[t - off];
        __syncthreads();
        if (t < 512) ps[t] += v;
        __syncthreads();
    }
    if (t < NBUK) {
        int c = h[t];
        lsb[t] = ps[t] - c;
        lb[t] = c ? atomicAdd(&bcur[t], c) : 0;
    }
    __syncthreads();
    for (int i = t; i < NBUK; i += 1024) h[i] = 0;
    __syncthreads();
    for (int i = t; i < cntE; i += 1024) {
        int e = base + i;
        int r = rows[e];
        int b = r >> BSHIFT;
        int q = __float2int_rn(vals[e] * VQ_ENC);
        if (q > 16383) q = 16383;
        int p = lsb[b] + atomicAdd(&h[b], 1);
        stage[p] = make_int2((int)(((unsigned)r << 14) | (unsigned)q), cols[e]);
    }
    __syncthreads();
    for (int i = t; i < cntE; i += 1024) {
        int2 rc = stage[i];
        int b = (int)((unsigned)rc.x >> 14) >> BSHIFT;
        int dst = lb[b] + (i - lsb[b]);
        if (dst < NBUK * CAP) recs[dst] = rc;
    }
}

// ---------------------------------------------------------------------------
// Exclusive scan over actual bucket counts (bcur[b] - b*CAP) -> compact boff
// ---------------------------------------------------------------------------
__global__ __launch_bounds__(512) void cnt_scan(const int* __restrict__ bcur,
                                                int* __restrict__ boff) {
    __shared__ int sh[512];
    int t = threadIdx.x;
    int c = (t < NBUK) ? (bcur[t] - t * CAP) : 0;
    sh[t] = c;
    __syncthreads();
    for (int off = 1; off < 512; off <<= 1) {
        int v = (t >= off) ? sh[t - off] : 0;
        __syncthreads();
        sh[t] += v;
        __syncthreads();
    }
    if (t < NBUK) boff[t] = sh[t] - c;  // exclusive
    if (t == 0) boff[NBUK] = NNZ;
}

// ---------------------------------------------------------------------------
// Phase B: per-bucket CSR build (col-block keyed). rec.x=(row<<14)|q14,
// rec.y=col. Output edge = (q14 << 18) | col (4 bytes).
// ---------------------------------------------------------------------------
__global__ __launch_bounds__(512) void build_csr(const int* __restrict__ boff,
                                                 const int2* __restrict__ recs,
                                                 int* __restrict__ row_ptr,
                                                 unsigned* __restrict__ edges) {
    __shared__ int h[BROWS * 8];   // per-(row, col-block) counts -> cursors
    __shared__ int ps[512];
    int b = blockIdx.x, t = threadIdx.x;
    int rbase = b * CAP;
    int obase = boff[b];
    int cnt = boff[b + 1] - obase;
    int row0 = b << BSHIFT;
    int nrows = N_TOTAL - row0;
    if (nrows > BROWS) nrows = BROWS;
    for (int i = t; i < BROWS * 8; i += 512) h[i] = 0;
    __syncthreads();
    for (int i = t; i < cnt; i += 512) {
        int2 rc = recs[rbase + i];
        int rrel = (int)(((unsigned)rc.x >> 14) & (BROWS - 1));
        int key = (rrel << 3) | (int)((unsigned)rc.y >> 15);
        atomicAdd(&h[key], 1);
    }
    __syncthreads();
    int loc[8];
    int s = 0;
#pragma unroll
    for (int j = 0; j < 8; ++j) { loc[j] = h[8 * t + j]; s += loc[j]; }
    ps[t] = s;
    __syncthreads();
    for (int off = 1; off < 512; off <<= 1) {
        int a = (t >= off) ? ps[t - off] : 0;
        __syncthreads();
        ps[t] += a;
        __syncthreads();
    }
    int run = obase + ((t == 0) ? 0 : ps[t - 1]);
    if (t < nrows) row_ptr[row0 + t] = run;
    if (b == NBUK - 1 && t == 0) row_ptr[N_TOTAL] = NNZ;
#pragma unroll
    for (int j = 0; j < 8; ++j) { h[8 * t + j] = run; run += loc[j]; }
    __syncthreads();
    for (int i = t; i < cnt; i += 512) {
        int2 rc = recs[rbase + i];
        unsigned rx = (unsigned)rc.x;
        int rrel = (int)((rx >> 14) & (BROWS - 1));
        int key = (rrel << 3) | (int)((unsigned)rc.y >> 15);
        int p = atomicAdd(&h[key], 1);
        edges[p] = (unsigned)rc.y | ((rx & 0x3FFFu) << 18);
    }
}

// ---------------------------------------------------------------------------
// Build fp8 all_emb (x64 scale) from f32 node_emb / hyper_emb, HW encode.
// ---------------------------------------------------------------------------
__global__ __launch_bounds__(256) void build_x_fp8(
    const float* __restrict__ node_emb, const float* __restrict__ hyper_emb,
    unsigned* __restrict__ xb) {
    int i = blockIdx.x * 256 + threadIdx.x;
    size_t base = (size_t)i * 4;
    const size_t NN = (size_t)N_NODES * DIM;
    if (base >= (size_t)N_TOTAL * DIM) return;
    float4 f;
    if (base < NN)
        f = *reinterpret_cast<const float4*>(node_emb + base);
    else
        f = *reinterpret_cast<const float4*>(hyper_emb + (base - NN));
    int lo = __builtin_amdgcn_cvt_pk_fp8_f32(f.x * SCALE_UP, f.y * SCALE_UP,
                                             0, false);
    int w = __builtin_amdgcn_cvt_pk_fp8_f32(f.z * SCALE_UP, f.w * SCALE_UP,
                                            lo, true);
    xb[i] = (unsigned)w;
}

// ---------------------------------------------------------------------------
// SpMM gather: 16 lanes per row (lane = 4 dims via one u32), 4 rows per wave,
// unroll x8 per row -> 32 outstanding 64B sectors per wave.
// ---------------------------------------------------------------------------
__global__ __launch_bounds__(256) void spmm_gather(
    const int* __restrict__ row_ptr, const unsigned* __restrict__ edges,
    const unsigned char* __restrict__ x, unsigned char* __restrict__ y,
    int nrows) {
    int gid = blockIdx.x * 256 + threadIdx.x;
    int row = gid >> 4;
    int lane = threadIdx.x & 15;
    if (row >= nrows) return;
    int beg = row_ptr[row], end = row_ptr[row + 1];
    float a0 = 0.f, a1 = 0.f, a2 = 0.f, a3 = 0.f;
    int k = beg;
    for (; k + 7 < end; k += 8) {
        unsigned e[8];
        unsigned g[8];
#pragma unroll
        for (int j = 0; j < 8; ++j) e[j] = edges[k + j];
#pragma unroll
        for (int j = 0; j < 8; ++j)
            g[j] = *(const unsigned*)(x + ((size_t)(e[j] & 0x3FFFFu) << 6) + lane * 4);
#pragma unroll
        for (int j = 0; j < 8; ++j) {
            float v = (float)(e[j] >> 18) * VQ_DEC;
            v2f lo = __builtin_amdgcn_cvt_pk_f32_fp8((int)g[j], false);
            v2f hi = __builtin_amdgcn_cvt_pk_f32_fp8((int)g[j], true);
            a0 = fmaf(v, lo[0], a0);
            a1 = fmaf(v, lo[1], a1);
            a2 = fmaf(v, hi[0], a2);
            a3 = fmaf(v, hi[1], a3);
        }
    }
    for (; k + 3 < end; k += 4) {
        unsigned e[4];
        unsigned g[4];
#pragma unroll
        for (int j = 0; j < 4; ++j) e[j] = edges[k + j];
#pragma unroll
        for (int j = 0; j < 4; ++j)
            g[j] = *(const unsigned*)(x + ((size_t)(e[j] & 0x3FFFFu) << 6) + lane * 4);
#pragma unroll
        for (int j = 0; j < 4; ++j) {
            float v = (float)(e[j] >> 18) * VQ_DEC;
            v2f lo = __builtin_amdgcn_cvt_pk_f32_fp8((int)g[j], false);
            v2f hi = __builtin_amdgcn_cvt_pk_f32_fp8((int)g[j], true);
            a0 = fmaf(v, lo[0], a0);
            a1 = fmaf(v, lo[1], a1);
            a2 = fmaf(v, hi[0], a2);
            a3 = fmaf(v, hi[1], a3);
        }
    }
    for (; k < end; ++k) {
        unsigned e = edges[k];
        unsigned g = *(const unsigned*)(x + ((size_t)(e & 0x3FFFFu) << 6) + lane * 4);
        float v = (float)(e >> 18) * VQ_DEC;
        v2f lo = __builtin_amdgcn_cvt_pk_f32_fp8((int)g, false);
        v2f hi = __builtin_amdgcn_cvt_pk_f32_fp8((int)g, true);
        a0 = fmaf(v, lo[0], a0);
        a1 = fmaf(v, lo[1], a1);
        a2 = fmaf(v, hi[0], a2);
        a3 = fmaf(v, hi[1], a3);
    }
    int plo = __builtin_amdgcn_cvt_pk_fp8_f32(a0, a1, 0, false);
    int pk = __builtin_amdgcn_cvt_pk_fp8_f32(a2, a3, plo, true);
    *(unsigned*)(y + ((size_t)row << 6) + lane * 4) = (unsigned)pk;
}

// ---------------------------------------------------------------------------
// Fused classifier: Z = log_softmax((node_emb + (y1+y2+y3)/64)/4 @ W + b)
// z staged in padded LDS (no recompute pass, no strided global writes);
// final write-out is linear & coalesced.
// ---------------------------------------------------------------------------
__global__ __launch_bounds__(256) void classify(
    const float* __restrict__ node_emb, const unsigned char* __restrict__ y1,
    const unsigned char* __restrict__ y2,
    const unsigned char* __restrict__ y3, const float* __restrict__ W,
    const float* __restrict__ bias, float* __restrict__ Z) {
    __shared__ float zl[256 * 51];  // 51-pad: conflict-free column writes
    int t = threadIdx.x;
    int block_base = blockIdx.x * 256;
    int row = block_base + t;
    if (row < N_NODES) {
        const float4* np =
            reinterpret_cast<const float4*>(node_emb + (size_t)row * DIM);
        const unsigned* p1 = (const unsigned*)(y1 + ((size_t)row << 6));
        const unsigned* p2 = (const unsigned*)(y2 + ((size_t)row << 6));
        const unsigned* p3 = (const unsigned*)(y3 + ((size_t)row << 6));
        float xr[DIM];
#pragma unroll
        for (int i = 0; i < DIM / 4; ++i) {
            float4 f = np[i];
            unsigned w1 = p1[i], w2 = p2[i], w3 = p3[i];
            v2f a0 = __builtin_amdgcn_cvt_pk_f32_fp8((int)w1, false);
            v2f a1 = __builtin_amdgcn_cvt_pk_f32_fp8((int)w1, true);
            v2f b0 = __builtin_amdgcn_cvt_pk_f32_fp8((int)w2, false);
            v2f b1 = __builtin_amdgcn_cvt_pk_f32_fp8((int)w2, true);
            v2f c0 = __builtin_amdgcn_cvt_pk_f32_fp8((int)w3, false);
            v2f c1 = __builtin_amdgcn_cvt_pk_f32_fp8((int)w3, true);
            xr[4 * i + 0] = (f.x + (a0[0] + b0[0] + c0[0]) * SCALE_DN) * 0.25f;
            xr[4 * i + 1] = (f.y + (a0[1] + b0[1] + c0[1]) * SCALE_DN) * 0.25f;
            xr[4 * i + 2] = (f.z + (a1[0] + b1[0] + c1[0]) * SCALE_DN) * 0.25f;
            xr[4 * i + 3] = (f.w + (a1[1] + b1[1] + c1[1]) * SCALE_DN) * 0.25f;
        }
        float m = -1e30f;
#pragma unroll 1
        for (int c = 0; c < NCLASS; ++c) {
            float d = bias[c];
#pragma unroll
            for (int k = 0; k < DIM; ++k) d = fmaf(xr[k], W[k * NCLASS + c], d);
            zl[t * 51 + c] = d;
            m = fmaxf(m, d);
        }
        float s = 0.f;
#pragma unroll 1
        for (int c = 0; c < NCLASS; ++c) s += __expf(zl[t * 51 + c] - m);
        float ls = m + __logf(s);
#pragma unroll 1
        for (int c = 0; c < NCLASS; ++c) zl[t * 51 + c] -= ls;
    }
    __syncthreads();
    int n_valid = N_NODES - block_base;
    if (n_valid > 256) n_valid = 256;
    if (n_valid < 0) n_valid = 0;
    int total = n_valid * NCLASS;
    float* zbase = Z + (size_t)block_base * NCLASS;
    for (int i = t; i < total; i += 256) {
        int r = i / NCLASS;
        int c = i - r * NCLASS;
        zbase[i] = zl[r * 51 + c];
    }
}

extern "C" void kernel_launch(void* const* d_in, const int* in_sizes, int n_in,
                              void* d_out, int out_size, void* d_ws, size_t ws_size,
                              hipStream_t stream) {
    const float* node_emb = (const float*)d_in[0];
    const float* hyper_emb = (const float*)d_in[1];
    const float* W = (const float*)d_in[2];
    const float* b = (const float*)d_in[3];
    const float* vals = (const float*)d_in[4];
    const int* rows = (const int*)d_in[5];
    const int* cols = (const int*)d_in[6];
    float* Z = (float*)d_out;

    const size_t BUF8 = (size_t)N_TOTAL * DIM;  // 12.8 MB (fp8)
    const size_t EDG = (size_t)NNZ * 4;         // 12.8 MB (packed u32)

    char* w = (char*)d_ws;
    unsigned char* xb = (unsigned char*)w;  w += BUF8;
    unsigned char* y1 = (unsigned char*)w;  w += BUF8;
    unsigned char* y2 = (unsigned char*)w;  w += BUF8;
    unsigned char* y3 = (unsigned char*)w;  w += BUF8;
    unsigned* edges = (unsigned*)w;         w += EDG;
    int* row_ptr = (int*)w;                 w += (size_t)(N_TOTAL + 1) * 4;
    int* boff = (int*)w;                    w += 2048;
    int* bcur = (int*)w;                    w += 2048;
    // recs (28.8 MB) in dedicated tail space (dead after build_csr).
    int2* recs = (int2*)w;

    // ---- Bucketed CSR build (fixed-capacity regions, no pre-histogram) ----
    init_cur<<<1, 512, 0, stream>>>(bcur);
    const int bin_blocks = (NNZ + EB - 1) / EB;  // 391
    bin_edges<<<bin_blocks, 1024, 0, stream>>>(rows, cols, vals, bcur, recs);
    cnt_scan<<<1, 512, 0, stream>>>(bcur, boff);
    build_csr<<<NBUK, 512, 0, stream>>>(boff, recs, row_ptr, edges);

    // ---- Build fp8 all_emb ----
    const int cvt_blocks = (int)(((size_t)N_TOTAL * DIM / 4 + 255) / 256);
    build_x_fp8<<<cvt_blocks, 256, 0, stream>>>(node_emb, hyper_emb,
                                                (unsigned*)xb);

    const int out_blocks = (N_NODES + 255) / 256;
    const int full_blocks = (N_TOTAL * 16 + 255) / 256;
    const int node_blocks = (N_NODES * 16 + 255) / 256;

    // L1: y1 = A x
    spmm_gather<<<full_blocks, 256, 0, stream>>>(row_ptr, edges, xb, y1,
                                                 N_TOTAL);
    // L2: y2 = A y1
    spmm_gather<<<full_blocks, 256, 0, stream>>>(row_ptr, edges, y1, y2,
                                                 N_TOTAL);
    // L3: y3 = A y2 (node rows only)
    spmm_gather<<<node_blocks, 256, 0, stream>>>(row_ptr, edges, y2, y3,
                                                 N_NODES);
    classify<<<out_blocks, 256, 0, stream>>>(node_emb, y1, y2, y3, W, b, Z);
}